// Round 1
// baseline (245.979 us; speedup 1.0000x reference)
//
#include <hip/hip_runtime.h>
#include <math.h>

#define OCT_EPS 1e-8f

// Abramowitz-Stegun 7.1.26 rational erf approximation, |err| <= 1.5e-7.
__device__ __forceinline__ float fast_erf(float x) {
    float z = fabsf(x);
    float t = __builtin_amdgcn_rcpf(fmaf(0.3275911f, z, 1.0f));
    float p = fmaf(1.061405429f, t, -1.453152027f);
    p = fmaf(p, t, 1.421413741f);
    p = fmaf(p, t, -0.284496736f);
    p = fmaf(p, t, 0.254829592f);
    p = p * t;
    float e = __expf(-z * z);          // v_exp_f32 path
    float r = fmaf(-p, e, 1.0f);
    return copysignf(r, x);
}

__device__ __forceinline__ float gelu_exact(float x) {
    return 0.5f * x * (1.0f + fast_erf(x * 0.70710678118654752f));
}

__global__ __launch_bounds__(256) void g2_ffn_kernel(
    const float* __restrict__ o,
    const float* __restrict__ W1,   // (32,2) row-major
    const float* __restrict__ b1,   // (32,)
    const float* __restrict__ W2,   // (3,32) row-major
    const float* __restrict__ b2,   // (3,)
    const float* __restrict__ alpha_p,
    float* __restrict__ out,
    int n_oct)
{
    int i = blockIdx.x * blockDim.x + threadIdx.x;
    if (i >= n_oct) return;

    const float4* ip = (const float4*)o;
    float4 lo = ip[2 * (size_t)i];
    float4 hi = ip[2 * (size_t)i + 1];

    float w = lo.x;
    // n^2 over the 7 imaginary components
    float n2 = lo.y * lo.y;
    n2 = fmaf(lo.z, lo.z, n2);
    n2 = fmaf(lo.w, lo.w, n2);
    n2 = fmaf(hi.x, hi.x, n2);
    n2 = fmaf(hi.y, hi.y, n2);
    n2 = fmaf(hi.z, hi.z, n2);
    n2 = fmaf(hi.w, hi.w, n2);
    float n = __builtin_amdgcn_sqrtf(n2);
    float s = fmaf(w, w, n2);          // |o|^2

    // MLP: 2 -> 32 (exact gelu) -> 3
    float a_acc = b2[0];
    float b_acc = b2[1];
    float c_acc = b2[2];
#pragma unroll
    for (int j = 0; j < 32; ++j) {
        float pre = fmaf(W1[2 * j], w, fmaf(W1[2 * j + 1], n, b1[j]));
        float h = gelu_exact(pre);
        a_acc = fmaf(W2[j], h, a_acc);
        b_acc = fmaf(W2[32 + j], h, b_acc);
        c_acc = fmaf(W2[64 + j], h, c_acc);
    }

    // upd = alpha_c * o + beta_c * e0   (octonion algebra collapsed)
    float alpha_c = fmaf(2.0f * b_acc, w, a_acc) + c_acc * fmaf(4.0f * w, w, -s);
    float beta_c  = -s * fmaf(2.0f * c_acc, w, b_acc);

    // |upd|^2 = a^2 s + 2 a b w + b^2
    float t2 = fmaf(alpha_c * alpha_c, s,
               fmaf(2.0f * alpha_c * beta_c, w, beta_c * beta_c));
    float nrm = __builtin_amdgcn_sqrtf(t2);
    float inv = __builtin_amdgcn_rcpf(fmaxf(nrm, OCT_EPS));

    float alpha_in = alpha_p[0];
    float lam = 1.0f / (1.0f + __expf(-alpha_in));
    float oml = 1.0f - lam;

    float la = lam * alpha_c * inv;   // scale applied to every component
    float lb = lam * beta_c * inv;    // extra on component 0

    float4 r0, r1;
    r0.x = fmaf(oml, lo.x, fmaf(la, lo.x, lb));
    r0.y = fmaf(oml, lo.y, la * lo.y);
    r0.z = fmaf(oml, lo.z, la * lo.z);
    r0.w = fmaf(oml, lo.w, la * lo.w);
    r1.x = fmaf(oml, hi.x, la * hi.x);
    r1.y = fmaf(oml, hi.y, la * hi.y);
    r1.z = fmaf(oml, hi.z, la * hi.z);
    r1.w = fmaf(oml, hi.w, la * hi.w);

    float4* op = (float4*)out;
    op[2 * (size_t)i]     = r0;
    op[2 * (size_t)i + 1] = r1;
}

extern "C" void kernel_launch(void* const* d_in, const int* in_sizes, int n_in,
                              void* d_out, int out_size, void* d_ws, size_t ws_size,
                              hipStream_t stream) {
    const float* o     = (const float*)d_in[0];
    const float* W1    = (const float*)d_in[1];
    const float* b1    = (const float*)d_in[2];
    const float* W2    = (const float*)d_in[3];
    const float* b2    = (const float*)d_in[4];
    const float* alpha = (const float*)d_in[5];
    float* out = (float*)d_out;

    int n_oct = in_sizes[0] / 8;
    int block = 256;
    int grid = (n_oct + block - 1) / block;
    g2_ffn_kernel<<<grid, block, 0, stream>>>(o, W1, b1, W2, b2, alpha, out, n_oct);
}